// Round 7
// baseline (260.474 us; speedup 1.0000x reference)
//
#include <hip/hip_runtime.h>
#include <hip/hip_bf16.h>

#define B_   4
#define T_   1024
#define DM   2048
#define QKVD 3072   // 64*(32+16)

typedef __attribute__((ext_vector_type(8))) short bf16x8;
typedef __attribute__((ext_vector_type(4))) short short4v;
typedef __attribute__((ext_vector_type(4))) float f32x4;
typedef __attribute__((ext_vector_type(16))) float f32x16;

__device__ __forceinline__ void load_lds16(const void* g, void* l) {
  __builtin_amdgcn_global_load_lds((const __attribute__((address_space(1))) void*)g,
                                   (__attribute__((address_space(3))) void*)l, 16, 0, 0);
}

__device__ __forceinline__ short f2bf(float f) {
  __hip_bfloat16 h = __float2bfloat16(f);
  return *reinterpret_cast<short*>(&h);
}

// fp32 -> bf16 convert for x (8.4M) and qkv_w (6.3M); grid-stride 4 float4
// per thread (3584 blocks vs 14336: less dispatch ramp). out_w conversion
// lives in the attn launch (z==4 stripe).
__global__ __launch_bounds__(256) void cvt_kernel(const float* __restrict__ x,
                                                  const float* __restrict__ w1,
                                                  short* __restrict__ xo,
                                                  short* __restrict__ w1o) {
  const unsigned base = blockIdx.x * 1024u + threadIdx.x;
#pragma unroll
  for (int k = 0; k < 4; ++k) {
    unsigned c = base + k * 256u;            // 0 .. 3670015
    const float* src;
    short* dst;
    if (c < 2097152u) {                      // x (boundary block-aligned)
      src = x; dst = xo;
    } else {                                 // qkv_w
      c -= 2097152u; src = w1; dst = w1o;
    }
    const float4 v = ((const float4*)src)[c];
    short4v o;
    o.x = f2bf(v.x); o.y = f2bf(v.y); o.z = f2bf(v.z); o.w = f2bf(v.w);
    ((short4v*)dst)[c] = o;
  }
}

// Shared GEMM K-loop: round-0 structure (128x128 tile, BK=32, 4 waves, 16 KB
// LDS single-buffer, 3 blocks/CU inter-block overlap, 2-bit XOR chunk swizzle,
// 0 conflicts) -- five pipelining variants all regressed (rounds 1-5), frozen.
// Round-7 change: 32x32x16 MFMA instead of 16x16x32. Same per-wave 64x64
// output (2x2 frags of 32x32), IDENTICAL ds_read count/bytes (8 b128/wave/
// K-step, same 8-pass bank-slot occupancy), but MFMA pipe time -17%
// (m119: 32x32 2495 TF vs 16x16 2176) and half the MFMA instructions.
// Frag layouts: A/B row(col) = lane&31, k = (lane>>5)*8 + e;
// C/D col = lane&31, row = (reg&3) + 8*(reg>>2) + 4*(lane>>5), reg in [0,16).
#define GEMM_PROLOGUE_AND_KLOOP(A_, B_ptr, K_)                                     \
  __shared__ short As[128 * 32];                                                   \
  __shared__ short Bs[128 * 32];                                                   \
  const int tid  = threadIdx.x;                                                    \
  const int lane = tid & 63;                                                       \
  const int wave = tid >> 6;                                                       \
  const int wm = wave >> 1, wn = wave & 1;                                         \
  const int l31 = lane & 31, half = lane >> 5;                                     \
  const int m0 = blockIdx.y * 128, n0 = blockIdx.x * 128;                          \
  f32x16 acc[2][2];                                                                \
  _Pragma("unroll") for (int i = 0; i < 2; ++i)                                    \
    _Pragma("unroll") for (int j = 0; j < 2; ++j)                                  \
      _Pragma("unroll") for (int e = 0; e < 16; ++e) acc[i][j][e] = 0.f;           \
  const int ca0 = tid, ca1 = tid + 256;                                            \
  const int sr0 = ca0 >> 2, sr1 = ca1 >> 2;                                        \
  const int sq0 = (ca0 & 3) ^ ((sr0 >> 1) & 3);                                    \
  const int sq1 = (ca1 & 3) ^ ((sr1 >> 1) & 3);                                    \
  const short* gA0 = A_ + (size_t)(m0 + sr0) * K_ + sq0 * 8;                       \
  const short* gA1 = A_ + (size_t)(m0 + sr1) * K_ + sq1 * 8;                       \
  const short* gB0 = B_ptr + (size_t)(n0 + sr0) * K_ + sq0 * 8;                    \
  const short* gB1 = B_ptr + (size_t)(n0 + sr1) * K_ + sq1 * 8;                    \
  short* lA0 = &As[ca0 * 8];                                                       \
  short* lA1 = &As[ca1 * 8];                                                       \
  short* lB0 = &Bs[ca0 * 8];                                                       \
  short* lB1 = &Bs[ca1 * 8];                                                       \
  const int sw32 = (l31 >> 1) & 3;                                                 \
  const int fo0 = ((0 + half) ^ sw32) * 8;  /* kc=0 chunk */                       \
  const int fo1 = ((2 + half) ^ sw32) * 8;  /* kc=1 chunk */                       \
  for (int k0 = 0; k0 < K_; k0 += 32) {                                            \
    __syncthreads();                                                               \
    load_lds16(gA0, lA0);                                                          \
    load_lds16(gA1, lA1);                                                          \
    load_lds16(gB0, lB0);                                                          \
    load_lds16(gB1, lB1);                                                          \
    gA0 += 32; gA1 += 32; gB0 += 32; gB1 += 32;                                    \
    __syncthreads();                                                               \
    bf16x8 af0[2], af1[2], bf0[2], bf1[2];                                         \
    _Pragma("unroll") for (int mb = 0; mb < 2; ++mb) {                             \
      af0[mb] = *(const bf16x8*)&As[(wm * 64 + mb * 32 + l31) * 32 + fo0];         \
      af1[mb] = *(const bf16x8*)&As[(wm * 64 + mb * 32 + l31) * 32 + fo1];         \
    }                                                                              \
    _Pragma("unroll") for (int nb = 0; nb < 2; ++nb) {                             \
      bf0[nb] = *(const bf16x8*)&Bs[(wn * 64 + nb * 32 + l31) * 32 + fo0];         \
      bf1[nb] = *(const bf16x8*)&Bs[(wn * 64 + nb * 32 + l31) * 32 + fo1];         \
    }                                                                              \
    _Pragma("unroll") for (int mb = 0; mb < 2; ++mb)                               \
      _Pragma("unroll") for (int nb = 0; nb < 2; ++nb) {                           \
        acc[mb][nb] = __builtin_amdgcn_mfma_f32_32x32x16_bf16(af0[mb], bf0[nb],    \
                                                              acc[mb][nb], 0, 0, 0);\
        acc[mb][nb] = __builtin_amdgcn_mfma_f32_32x32x16_bf16(af1[mb], bf1[nb],    \
                                                              acc[mb][nb], 0, 0, 0);\
      }                                                                            \
  }

// QKV projection with fused bias + YaRN RoPE + SM_SCALE; q/k -> bf16 qkvb,
// v -> bf16 vT[b][kv][d][t]. With 32x32 frags the RoPE pair (i, i+32) lands
// in the SAME lane+reg of adjacent nb frags: x1=acc[mb][0][reg],
// x2=acc[mb][1][reg] -- pure in-register rotation, one invf per lane.
__global__ __launch_bounds__(256) void gemm_qkv(const short* __restrict__ A,
                                                const short* __restrict__ Bw,
                                                const float* __restrict__ bias,
                                                short* __restrict__ qkvb,
                                                short* __restrict__ vT) {
  GEMM_PROLOGUE_AND_KLOOP(A, Bw, 2048)

  if (blockIdx.x < 20) {
    // q (cols<2048) or k (2048..2559): bias + rope (+0.125 scale for q)
    const float scale = (blockIdx.x < 16) ? 0.125f : 1.0f;
    const float fi = (float)l31;                 // head-dim rotation index
    const float freq = __powf(150000.f, fi * (1.f / 32.f));
    float ramp = (fi - 4.3707300f) * (1.f / 9.3052397f);
    ramp = fminf(fmaxf(ramp, 0.f), 1.f);
    const float invf = ramp / (32.f * freq) + (1.f - ramp) / freq;
    const float bv0 = bias[n0 + wn * 64 + l31];
    const float bv1 = bias[n0 + wn * 64 + 32 + l31];
    short* qbase = qkvb + n0 + wn * 64 + l31;
#pragma unroll
    for (int mb = 0; mb < 2; ++mb)
#pragma unroll
      for (int reg = 0; reg < 16; ++reg) {
        const int row = m0 + wm * 64 + mb * 32 + (reg & 3) + 8 * (reg >> 2) + 4 * half;
        const float ft = (float)(row & 1023);    // per-batch position
        const float ph = ft * invf;
        const float c = __cosf(ph) * 1.3465736f; // concentration = 0.1*ln(32)+1
        const float s = __sinf(ph) * 1.3465736f;
        const float x1 = acc[mb][0][reg] + bv0;
        const float x2 = acc[mb][1][reg] + bv1;
        short* qp = qbase + (size_t)row * QKVD;
        qp[0]  = f2bf((x1 * c - x2 * s) * scale);
        qp[32] = f2bf((x2 * c + x1 * s) * scale);
      }
  } else {
    // v (cols 2560..3071): bias, write transposed vT[b][kv][d][t], short4 packs
#pragma unroll
    for (int nb = 0; nb < 2; ++nb) {
      const int col = n0 + wn * 64 + nb * 32 + l31;
      const float bvv = bias[col];
      const int d = col & 63;
      const int kvh = (col - 2560) >> 6;
#pragma unroll
      for (int mb = 0; mb < 2; ++mb)
#pragma unroll
        for (int q4 = 0; q4 < 4; ++q4) {
          const int rb = m0 + wm * 64 + mb * 32 + 8 * q4 + 4 * half;
          const int bb = rb >> 10, tt = rb & 1023;
          short4v st;
          st.x = f2bf(acc[mb][nb][q4 * 4 + 0] + bvv);
          st.y = f2bf(acc[mb][nb][q4 * 4 + 1] + bvv);
          st.z = f2bf(acc[mb][nb][q4 * 4 + 2] + bvv);
          st.w = f2bf(acc[mb][nb][q4 * 4 + 3] + bvv);
          *(short4v*)&vT[(size_t)((bb * 8 + kvh) * 64 + d) * 1024 + tt] = st;
        }
    }
  }
}

// Output projection: C fp32 = A bf16 * B^T bf16 + bias (lanes 0-31 write
// 128B-coalesced column runs with the 32x32 C layout).
__global__ __launch_bounds__(256) void gemm_out(const short* __restrict__ A,
                                                const short* __restrict__ Bw,
                                                const float* __restrict__ bias,
                                                float* __restrict__ C) {
  GEMM_PROLOGUE_AND_KLOOP(A, Bw, 2048)
#pragma unroll
  for (int nb = 0; nb < 2; ++nb) {
    const int col = n0 + wn * 64 + nb * 32 + l31;
    const float bv = bias[col];
#pragma unroll
    for (int mb = 0; mb < 2; ++mb)
#pragma unroll
      for (int reg = 0; reg < 16; ++reg) {
        const int row = m0 + wm * 64 + mb * 32 + (reg & 3) + 8 * (reg >> 2) + 4 * half;
        C[(size_t)row * DM + col] = acc[mb][nb][reg] + bv;
      }
  }
}

// MFMA flash-style sliding-window attention, all-bf16 inputs (unchanged from
// round 6: dead-skip + out_w cvt stripe, both verified).
#define LSTR 72
__global__ __launch_bounds__(256, 4) void attn_kernel(const short* __restrict__ qkvb,
                                                      const short* __restrict__ vT,
                                                      const float* __restrict__ sinks,
                                                      short* __restrict__ attn_out,
                                                      const float* __restrict__ ow,
                                                      short* __restrict__ wob) {
  const int tid = threadIdx.x;

  if (blockIdx.z == 4) {
    // out_w conversion stripe: 256 blocks x 256 threads x 16 float4 = 2048x2048
    const unsigned id = blockIdx.y * 32u + blockIdx.x;          // 0..255
    const unsigned base = id * 4096u + (unsigned)tid;           // float4 index
#pragma unroll
    for (int k = 0; k < 16; ++k) {
      const float4 v = ((const float4*)ow)[base + k * 256u];
      short4v o;
      o.x = f2bf(v.x); o.y = f2bf(v.y); o.z = f2bf(v.z); o.w = f2bf(v.w);
      ((short4v*)wob)[base + k * 256u] = o;
    }
    return;
  }

  __shared__ short Kb[64 * 64];        // [key][dim], swizzled chunks
  __shared__ short Vt[64 * 64];        // [dim][key], swizzled chunks
  __shared__ short Pl[4][32 * LSTR];   // per-wave [query][key]
  const int lane = tid & 63;
  const int m    = tid >> 6;
  const int r15  = lane & 15, quad = lane >> 4;
  const int t0 = blockIdx.x * 32;
  const int kv = blockIdx.y;
  const int b  = blockIdx.z;
  const int swf = r15 & 7;

  bf16x8 qf[2][2];
#pragma unroll
  for (int tm = 0; tm < 2; ++tm)
#pragma unroll
    for (int kc = 0; kc < 2; ++kc)
      qf[tm][kc] = *(const bf16x8*)&qkvb[(size_t)(b * T_ + t0 + tm * 16 + r15) * QKVD
                                         + kv * 256 + m * 64 + kc * 32 + quad * 8];

  f32x4 oacc[2][4];
#pragma unroll
  for (int i = 0; i < 2; ++i)
#pragma unroll
    for (int j = 0; j < 4; ++j) oacc[i][j] = {0.f, 0.f, 0.f, 0.f};
  float lf[8];
#pragma unroll
  for (int i = 0; i < 8; ++i) lf[i] = 0.f;

  const short* kbase = qkvb + (size_t)b * T_ * QKVD + 2048 + kv * 64;
  const short* vbase = vT + (size_t)((b * 8 + kv) * 64) * 1024;

  // 64-aligned key tiles covering [max(0, t0-127), t0+31]
  const int jt_lo = (t0 >= 127) ? ((t0 - 127) >> 6) : 0;
  const int jt_hi = (t0 + 31) >> 6;

  for (int jt = jt_lo; jt <= jt_hi; ++jt) {
    const int j0 = jt * 64;
    __syncthreads();  // previous tile fully consumed
#pragma unroll
    for (int i = 0; i < 2; ++i) {
      const int c = i * 256 + tid;
      const int r = c >> 3, qs = (c & 7) ^ (r & 7);
      load_lds16(kbase + (size_t)(j0 + r) * QKVD + qs * 8, &Kb[c * 8]);
      load_lds16(vbase + (size_t)r * 1024 + j0 + qs * 8, &Vt[c * 8]);
    }
    __syncthreads();  // vmcnt(0) drain -> LDS ready

    // per-fragment validity (uniform across wave)
    bool deadf[2][4];
#pragma unroll
    for (int tm = 0; tm < 2; ++tm)
#pragma unroll
      for (int tn = 0; tn < 4; ++tn) {
        const int qlo = t0 + tm * 16, klo = j0 + tn * 16;
        deadf[tm][tn] = (klo > qlo + 15) || (klo + 15 <= qlo - 128);
      }

    // S = Q K^T : C/D layout col(key)=tn*16+r15, row(query)=tm*16+quad*4+v
    f32x4 sacc[2][4];
#pragma unroll
    for (int i = 0; i < 2; ++i)
#pragma unroll
      for (int j = 0; j < 4; ++j) sacc[i][j] = {0.f, 0.f, 0.f, 0.f};
#pragma unroll
    for (int kc = 0; kc < 2; ++kc) {
      bf16x8 bk[4];
#pragma unroll
      for (int tn = 0; tn < 4; ++tn)
        bk[tn] = *(const bf16x8*)&Kb[(tn * 16 + r15) * 64 + ((kc * 4 + quad) ^ swf) * 8];
#pragma unroll
      for (int tm = 0; tm < 2; ++tm)
#pragma unroll
        for (int tn = 0; tn < 4; ++tn)
          if (!deadf[tm][tn])
            sacc[tm][tn] = __builtin_amdgcn_mfma_f32_16x16x32_bf16(qf[tm][kc], bk[tn],
                                                                   sacc[tm][tn], 0, 0, 0);
    }

    // mask + exp + row-sum partials + P to per-wave LDS (dead frags: store 0)
    short* pl = &Pl[m][0];
#pragma unroll
    for (int tm = 0; tm < 2; ++tm)
#pragma unroll
      for (int v = 0; v < 4; ++v) {
        const int ql = tm * 16 + quad * 4 + v;
        const int t = t0 + ql;
        float lsum = 0.f;
#pragma unroll
        for (int tn = 0; tn < 4; ++tn) {
          if (deadf[tm][tn]) {
            pl[ql * LSTR + tn * 16 + r15] = 0;
          } else {
            const int j = j0 + tn * 16 + r15;
            const bool valid = (unsigned)(t - j) <= 127u;
            const float e = valid ? __expf(sacc[tm][tn][v]) : 0.f;
            lsum += e;
            pl[ql * LSTR + tn * 16 + r15] = f2bf(e);
          }
        }
        lf[tm * 4 + v] += lsum;
      }

    // O += P V (A from Pl, B from Vt; same-wave RAW via lgkmcnt)
#pragma unroll
    for (int kc = 0; kc < 2; ++kc) {
      bf16x8 ap[2], bv[4];
#pragma unroll
      for (int tm = 0; tm < 2; ++tm)
        ap[tm] = *(const bf16x8*)&pl[(tm * 16 + r15) * LSTR + kc * 32 + quad * 8];
#pragma unroll
      for (int tn = 0; tn < 4; ++tn)
        bv[tn] = *(const bf16x8*)&Vt[(tn * 16 + r15) * 64 + ((kc * 4 + quad) ^ swf) * 8];
#pragma unroll
      for (int tm = 0; tm < 2; ++tm)
#pragma unroll
        for (int tn = 0; tn < 4; ++tn)
          oacc[tm][tn] = __builtin_amdgcn_mfma_f32_16x16x32_bf16(ap[tm], bv[tn],
                                                                 oacc[tm][tn], 0, 0, 0);
    }
  }

  // reduce l over the 16-lane r15 group, fold sink, normalize, store bf16
#pragma unroll
  for (int i = 0; i < 8; ++i) {
    float v = lf[i];
    v += __shfl_xor(v, 1, 64);
    v += __shfl_xor(v, 2, 64);
    v += __shfl_xor(v, 4, 64);
    v += __shfl_xor(v, 8, 64);
    lf[i] = v;
  }
  const int h = kv * 4 + m;
  const float snk = __expf(sinks[h]);
#pragma unroll
  for (int tm = 0; tm < 2; ++tm)
#pragma unroll
    for (int v = 0; v < 4; ++v) {
      const float inv = 1.f / (lf[tm * 4 + v] + snk);
      const int t = t0 + tm * 16 + quad * 4 + v;
      short* op = attn_out + (size_t)(b * T_ + t) * DM + h * 64;
#pragma unroll
      for (int tn = 0; tn < 4; ++tn)
        op[tn * 16 + r15] = f2bf(oacc[tm][tn][v] * inv);
    }
}

extern "C" void kernel_launch(void* const* d_in, const int* in_sizes, int n_in,
                              void* d_out, int out_size, void* d_ws, size_t ws_size,
                              hipStream_t stream) {
  const float* x      = (const float*)d_in[0];   // fp32 (B,T,DM)
  const float* qkv_w  = (const float*)d_in[1];   // fp32 (3072,2048)
  const float* qkv_b  = (const float*)d_in[2];   // fp32 (3072,)
  const float* out_w  = (const float*)d_in[3];   // fp32 (2048,2048)
  const float* out_b  = (const float*)d_in[4];   // fp32 (2048,)
  const float* sinks  = (const float*)d_in[5];   // fp32 (32,)

  // ws layout (67.1 MB):
  //   [0, 25165824)            qkvb bf16 (4096 x 3072; v section unused)
  //   [25165824, 29360128)     vT bf16 [b][kv][64][1024]
  //   [29360128, 46137344)     x bf16, later aliased as attn bf16 out
  //   [46137344, 58720256)     qkv_w bf16
  //   [58720256, 67108864)     out_w bf16
  char* ws = (char*)d_ws;
  short* qkvb = (short*)ws;
  short* vT   = (short*)(ws + 25165824);
  short* xb   = (short*)(ws + 29360128);
  short* wqb  = (short*)(ws + 46137344);
  short* wob  = (short*)(ws + 58720256);
  short* attn = xb;                            // aliased: xb dead after gemm_qkv
  float* out  = (float*)d_out;

  cvt_kernel<<<3584, 256, 0, stream>>>(x, qkv_w, xb, wqb);
  gemm_qkv<<<dim3(QKVD / 128, 4096 / 128), 256, 0, stream>>>(xb, wqb, qkv_b, qkvb, vT);
  attn_kernel<<<dim3(T_ / 32, 8, B_ + 1), 256, 0, stream>>>(qkvb, vT, sinks, attn,
                                                            out_w, wob);
  gemm_out<<<dim3(DM / 128, 4096 / 128), 256, 0, stream>>>(attn, wob, out_b, out);
}

// Round 8
// 260.103 us; speedup vs baseline: 1.0014x; 1.0014x over previous
//
#include <hip/hip_runtime.h>
#include <hip/hip_bf16.h>

#define B_   4
#define T_   1024
#define DM   2048
#define QKVD 3072   // 64*(32+16)

typedef __attribute__((ext_vector_type(8))) short bf16x8;
typedef __attribute__((ext_vector_type(4))) short short4v;
typedef __attribute__((ext_vector_type(4))) float f32x4;
typedef __attribute__((ext_vector_type(16))) float f32x16;

__device__ __forceinline__ void load_lds16(const void* g, void* l) {
  __builtin_amdgcn_global_load_lds((const __attribute__((address_space(1))) void*)g,
                                   (__attribute__((address_space(3))) void*)l, 16, 0, 0);
}

__device__ __forceinline__ short f2bf(float f) {
  __hip_bfloat16 h = __float2bfloat16(f);
  return *reinterpret_cast<short*>(&h);
}

// fp32 -> bf16 convert for x (8.4M) and qkv_w (6.3M) (round-6 form). out_w
// conversion lives in the attn launch (z==4 stripe).
__global__ __launch_bounds__(256) void cvt_kernel(const float* __restrict__ x,
                                                  const float* __restrict__ w1,
                                                  short* __restrict__ xo,
                                                  short* __restrict__ w1o) {
  unsigned c = blockIdx.x * 256u + threadIdx.x;  // 0 .. 3670015
  const float* src;
  short* dst;
  if (c < 2097152u) {                 // x
    src = x; dst = xo;
  } else {                            // qkv_w
    c -= 2097152u; src = w1; dst = w1o;
  }
  const float4 v = ((const float4*)src)[c];
  short4v o;
  o.x = f2bf(v.x); o.y = f2bf(v.y); o.z = f2bf(v.z); o.w = f2bf(v.w);
  ((short4v*)dst)[c] = o;
}

// Shared GEMM K-loop: 128x128 tile, BK=32, 4 waves, 16 KB LDS single-buffer,
// 3 blocks/CU inter-block overlap (five pipelining variants all regressed,
// rounds 1-5 -- frozen). 32x32x16 MFMA (r7: MFMA pipe -17%, qkv 79.8->72.1
// in-session). Round-8 fix: swizzle f(r) = ((r>>1)^(r>>3))&3 instead of
// (r>>1)&3. r7's f was invariant under r->r+16, so lanes l and l+16 (rows
// 16 apart) hit the SAME bank-quad at different addresses -> measured
// 6.29M conflict cycles/dispatch (32/wave/K-step). The r>>3 term makes rows
// {r, r+8, r+16, r+24} map to 4 distinct quads; every consecutive 8-lane
// group covers all 8 bank-quads exactly once. Chunk-per-lane is forced by
// the MFMA operand layout (no k-permutation freedom), storage swizzle is
// the only lever.
// Frag layouts: A/B row(col) = lane&31, k = (lane>>5)*8 + e;
// C/D col = lane&31, row = (reg&3) + 8*(reg>>2) + 4*(lane>>5), reg in [0,16).
#define GEMM_PROLOGUE_AND_KLOOP(A_, B_ptr, K_)                                     \
  __shared__ short As[128 * 32];                                                   \
  __shared__ short Bs[128 * 32];                                                   \
  const int tid  = threadIdx.x;                                                    \
  const int lane = tid & 63;                                                       \
  const int wave = tid >> 6;                                                       \
  const int wm = wave >> 1, wn = wave & 1;                                         \
  const int l31 = lane & 31, half = lane >> 5;                                     \
  const int m0 = blockIdx.y * 128, n0 = blockIdx.x * 128;                          \
  f32x16 acc[2][2];                                                                \
  _Pragma("unroll") for (int i = 0; i < 2; ++i)                                    \
    _Pragma("unroll") for (int j = 0; j < 2; ++j)                                  \
      _Pragma("unroll") for (int e = 0; e < 16; ++e) acc[i][j][e] = 0.f;           \
  const int ca0 = tid, ca1 = tid + 256;                                            \
  const int sr0 = ca0 >> 2, sr1 = ca1 >> 2;                                        \
  const int sq0 = (ca0 & 3) ^ (((sr0 >> 1) ^ (sr0 >> 3)) & 3);                     \
  const int sq1 = (ca1 & 3) ^ (((sr1 >> 1) ^ (sr1 >> 3)) & 3);                     \
  const short* gA0 = A_ + (size_t)(m0 + sr0) * K_ + sq0 * 8;                       \
  const short* gA1 = A_ + (size_t)(m0 + sr1) * K_ + sq1 * 8;                       \
  const short* gB0 = B_ptr + (size_t)(n0 + sr0) * K_ + sq0 * 8;                    \
  const short* gB1 = B_ptr + (size_t)(n0 + sr1) * K_ + sq1 * 8;                    \
  short* lA0 = &As[ca0 * 8];                                                       \
  short* lA1 = &As[ca1 * 8];                                                       \
  short* lB0 = &Bs[ca0 * 8];                                                       \
  short* lB1 = &Bs[ca1 * 8];                                                       \
  const int sw32 = ((l31 >> 1) ^ (l31 >> 3)) & 3;                                  \
  const int fo0 = ((0 + half) ^ sw32) * 8;  /* kc=0 chunk */                       \
  const int fo1 = ((2 + half) ^ sw32) * 8;  /* kc=1 chunk */                       \
  for (int k0 = 0; k0 < K_; k0 += 32) {                                            \
    __syncthreads();                                                               \
    load_lds16(gA0, lA0);                                                          \
    load_lds16(gA1, lA1);                                                          \
    load_lds16(gB0, lB0);                                                          \
    load_lds16(gB1, lB1);                                                          \
    gA0 += 32; gA1 += 32; gB0 += 32; gB1 += 32;                                    \
    __syncthreads();                                                               \
    bf16x8 af0[2], af1[2], bf0[2], bf1[2];                                         \
    _Pragma("unroll") for (int mb = 0; mb < 2; ++mb) {                             \
      af0[mb] = *(const bf16x8*)&As[(wm * 64 + mb * 32 + l31) * 32 + fo0];         \
      af1[mb] = *(const bf16x8*)&As[(wm * 64 + mb * 32 + l31) * 32 + fo1];         \
    }                                                                              \
    _Pragma("unroll") for (int nb = 0; nb < 2; ++nb) {                             \
      bf0[nb] = *(const bf16x8*)&Bs[(wn * 64 + nb * 32 + l31) * 32 + fo0];         \
      bf1[nb] = *(const bf16x8*)&Bs[(wn * 64 + nb * 32 + l31) * 32 + fo1];         \
    }                                                                              \
    _Pragma("unroll") for (int mb = 0; mb < 2; ++mb)                               \
      _Pragma("unroll") for (int nb = 0; nb < 2; ++nb) {                           \
        acc[mb][nb] = __builtin_amdgcn_mfma_f32_32x32x16_bf16(af0[mb], bf0[nb],    \
                                                              acc[mb][nb], 0, 0, 0);\
        acc[mb][nb] = __builtin_amdgcn_mfma_f32_32x32x16_bf16(af1[mb], bf1[nb],    \
                                                              acc[mb][nb], 0, 0, 0);\
      }                                                                            \
  }

// QKV projection with fused bias + YaRN RoPE + SM_SCALE; q/k -> bf16 qkvb,
// v -> bf16 vT[b][kv][d][t]. With 32x32 frags the RoPE pair (i, i+32) lands
// in the SAME lane+reg of adjacent nb frags: x1=acc[mb][0][reg],
// x2=acc[mb][1][reg] -- pure in-register rotation, one invf per lane.
__global__ __launch_bounds__(256) void gemm_qkv(const short* __restrict__ A,
                                                const short* __restrict__ Bw,
                                                const float* __restrict__ bias,
                                                short* __restrict__ qkvb,
                                                short* __restrict__ vT) {
  GEMM_PROLOGUE_AND_KLOOP(A, Bw, 2048)

  if (blockIdx.x < 20) {
    // q (cols<2048) or k (2048..2559): bias + rope (+0.125 scale for q)
    const float scale = (blockIdx.x < 16) ? 0.125f : 1.0f;
    const float fi = (float)l31;                 // head-dim rotation index
    const float freq = __powf(150000.f, fi * (1.f / 32.f));
    float ramp = (fi - 4.3707300f) * (1.f / 9.3052397f);
    ramp = fminf(fmaxf(ramp, 0.f), 1.f);
    const float invf = ramp / (32.f * freq) + (1.f - ramp) / freq;
    const float bv0 = bias[n0 + wn * 64 + l31];
    const float bv1 = bias[n0 + wn * 64 + 32 + l31];
    short* qbase = qkvb + n0 + wn * 64 + l31;
#pragma unroll
    for (int mb = 0; mb < 2; ++mb)
#pragma unroll
      for (int reg = 0; reg < 16; ++reg) {
        const int row = m0 + wm * 64 + mb * 32 + (reg & 3) + 8 * (reg >> 2) + 4 * half;
        const float ft = (float)(row & 1023);    // per-batch position
        const float ph = ft * invf;
        const float c = __cosf(ph) * 1.3465736f; // concentration = 0.1*ln(32)+1
        const float s = __sinf(ph) * 1.3465736f;
        const float x1 = acc[mb][0][reg] + bv0;
        const float x2 = acc[mb][1][reg] + bv1;
        short* qp = qbase + (size_t)row * QKVD;
        qp[0]  = f2bf((x1 * c - x2 * s) * scale);
        qp[32] = f2bf((x2 * c + x1 * s) * scale);
      }
  } else {
    // v (cols 2560..3071): bias, write transposed vT[b][kv][d][t], short4 packs
#pragma unroll
    for (int nb = 0; nb < 2; ++nb) {
      const int col = n0 + wn * 64 + nb * 32 + l31;
      const float bvv = bias[col];
      const int d = col & 63;
      const int kvh = (col - 2560) >> 6;
#pragma unroll
      for (int mb = 0; mb < 2; ++mb)
#pragma unroll
        for (int q4 = 0; q4 < 4; ++q4) {
          const int rb = m0 + wm * 64 + mb * 32 + 8 * q4 + 4 * half;
          const int bb = rb >> 10, tt = rb & 1023;
          short4v st;
          st.x = f2bf(acc[mb][nb][q4 * 4 + 0] + bvv);
          st.y = f2bf(acc[mb][nb][q4 * 4 + 1] + bvv);
          st.z = f2bf(acc[mb][nb][q4 * 4 + 2] + bvv);
          st.w = f2bf(acc[mb][nb][q4 * 4 + 3] + bvv);
          *(short4v*)&vT[(size_t)((bb * 8 + kvh) * 64 + d) * 1024 + tt] = st;
        }
    }
  }
}

// Output projection: C fp32 = A bf16 * B^T bf16 + bias (lanes 0-31 write
// 128B-coalesced column runs with the 32x32 C layout).
__global__ __launch_bounds__(256) void gemm_out(const short* __restrict__ A,
                                                const short* __restrict__ Bw,
                                                const float* __restrict__ bias,
                                                float* __restrict__ C) {
  GEMM_PROLOGUE_AND_KLOOP(A, Bw, 2048)
#pragma unroll
  for (int nb = 0; nb < 2; ++nb) {
    const int col = n0 + wn * 64 + nb * 32 + l31;
    const float bv = bias[col];
#pragma unroll
    for (int mb = 0; mb < 2; ++mb)
#pragma unroll
      for (int reg = 0; reg < 16; ++reg) {
        const int row = m0 + wm * 64 + mb * 32 + (reg & 3) + 8 * (reg >> 2) + 4 * half;
        C[(size_t)row * DM + col] = acc[mb][nb][reg] + bv;
      }
  }
}

// MFMA flash-style sliding-window attention, all-bf16 inputs (unchanged from
// round 6: dead-skip + out_w cvt stripe, both verified).
#define LSTR 72
__global__ __launch_bounds__(256, 4) void attn_kernel(const short* __restrict__ qkvb,
                                                      const short* __restrict__ vT,
                                                      const float* __restrict__ sinks,
                                                      short* __restrict__ attn_out,
                                                      const float* __restrict__ ow,
                                                      short* __restrict__ wob) {
  const int tid = threadIdx.x;

  if (blockIdx.z == 4) {
    // out_w conversion stripe: 256 blocks x 256 threads x 16 float4 = 2048x2048
    const unsigned id = blockIdx.y * 32u + blockIdx.x;          // 0..255
    const unsigned base = id * 4096u + (unsigned)tid;           // float4 index
#pragma unroll
    for (int k = 0; k < 16; ++k) {
      const float4 v = ((const float4*)ow)[base + k * 256u];
      short4v o;
      o.x = f2bf(v.x); o.y = f2bf(v.y); o.z = f2bf(v.z); o.w = f2bf(v.w);
      ((short4v*)wob)[base + k * 256u] = o;
    }
    return;
  }

  __shared__ short Kb[64 * 64];        // [key][dim], swizzled chunks
  __shared__ short Vt[64 * 64];        // [dim][key], swizzled chunks
  __shared__ short Pl[4][32 * LSTR];   // per-wave [query][key]
  const int lane = tid & 63;
  const int m    = tid >> 6;
  const int r15  = lane & 15, quad = lane >> 4;
  const int t0 = blockIdx.x * 32;
  const int kv = blockIdx.y;
  const int b  = blockIdx.z;
  const int swf = r15 & 7;

  bf16x8 qf[2][2];
#pragma unroll
  for (int tm = 0; tm < 2; ++tm)
#pragma unroll
    for (int kc = 0; kc < 2; ++kc)
      qf[tm][kc] = *(const bf16x8*)&qkvb[(size_t)(b * T_ + t0 + tm * 16 + r15) * QKVD
                                         + kv * 256 + m * 64 + kc * 32 + quad * 8];

  f32x4 oacc[2][4];
#pragma unroll
  for (int i = 0; i < 2; ++i)
#pragma unroll
    for (int j = 0; j < 4; ++j) oacc[i][j] = {0.f, 0.f, 0.f, 0.f};
  float lf[8];
#pragma unroll
  for (int i = 0; i < 8; ++i) lf[i] = 0.f;

  const short* kbase = qkvb + (size_t)b * T_ * QKVD + 2048 + kv * 64;
  const short* vbase = vT + (size_t)((b * 8 + kv) * 64) * 1024;

  // 64-aligned key tiles covering [max(0, t0-127), t0+31]
  const int jt_lo = (t0 >= 127) ? ((t0 - 127) >> 6) : 0;
  const int jt_hi = (t0 + 31) >> 6;

  for (int jt = jt_lo; jt <= jt_hi; ++jt) {
    const int j0 = jt * 64;
    __syncthreads();  // previous tile fully consumed
#pragma unroll
    for (int i = 0; i < 2; ++i) {
      const int c = i * 256 + tid;
      const int r = c >> 3, qs = (c & 7) ^ (r & 7);
      load_lds16(kbase + (size_t)(j0 + r) * QKVD + qs * 8, &Kb[c * 8]);
      load_lds16(vbase + (size_t)r * 1024 + j0 + qs * 8, &Vt[c * 8]);
    }
    __syncthreads();  // vmcnt(0) drain -> LDS ready

    // per-fragment validity (uniform across wave)
    bool deadf[2][4];
#pragma unroll
    for (int tm = 0; tm < 2; ++tm)
#pragma unroll
      for (int tn = 0; tn < 4; ++tn) {
        const int qlo = t0 + tm * 16, klo = j0 + tn * 16;
        deadf[tm][tn] = (klo > qlo + 15) || (klo + 15 <= qlo - 128);
      }

    // S = Q K^T : C/D layout col(key)=tn*16+r15, row(query)=tm*16+quad*4+v
    f32x4 sacc[2][4];
#pragma unroll
    for (int i = 0; i < 2; ++i)
#pragma unroll
      for (int j = 0; j < 4; ++j) sacc[i][j] = {0.f, 0.f, 0.f, 0.f};
#pragma unroll
    for (int kc = 0; kc < 2; ++kc) {
      bf16x8 bk[4];
#pragma unroll
      for (int tn = 0; tn < 4; ++tn)
        bk[tn] = *(const bf16x8*)&Kb[(tn * 16 + r15) * 64 + ((kc * 4 + quad) ^ swf) * 8];
#pragma unroll
      for (int tm = 0; tm < 2; ++tm)
#pragma unroll
        for (int tn = 0; tn < 4; ++tn)
          if (!deadf[tm][tn])
            sacc[tm][tn] = __builtin_amdgcn_mfma_f32_16x16x32_bf16(qf[tm][kc], bk[tn],
                                                                   sacc[tm][tn], 0, 0, 0);
    }

    // mask + exp + row-sum partials + P to per-wave LDS (dead frags: store 0)
    short* pl = &Pl[m][0];
#pragma unroll
    for (int tm = 0; tm < 2; ++tm)
#pragma unroll
      for (int v = 0; v < 4; ++v) {
        const int ql = tm * 16 + quad * 4 + v;
        const int t = t0 + ql;
        float lsum = 0.f;
#pragma unroll
        for (int tn = 0; tn < 4; ++tn) {
          if (deadf[tm][tn]) {
            pl[ql * LSTR + tn * 16 + r15] = 0;
          } else {
            const int j = j0 + tn * 16 + r15;
            const bool valid = (unsigned)(t - j) <= 127u;
            const float e = valid ? __expf(sacc[tm][tn][v]) : 0.f;
            lsum += e;
            pl[ql * LSTR + tn * 16 + r15] = f2bf(e);
          }
        }
        lf[tm * 4 + v] += lsum;
      }

    // O += P V (A from Pl, B from Vt; same-wave RAW via lgkmcnt)
#pragma unroll
    for (int kc = 0; kc < 2; ++kc) {
      bf16x8 ap[2], bv[4];
#pragma unroll
      for (int tm = 0; tm < 2; ++tm)
        ap[tm] = *(const bf16x8*)&pl[(tm * 16 + r15) * LSTR + kc * 32 + quad * 8];
#pragma unroll
      for (int tn = 0; tn < 4; ++tn)
        bv[tn] = *(const bf16x8*)&Vt[(tn * 16 + r15) * 64 + ((kc * 4 + quad) ^ swf) * 8];
#pragma unroll
      for (int tm = 0; tm < 2; ++tm)
#pragma unroll
        for (int tn = 0; tn < 4; ++tn)
          oacc[tm][tn] = __builtin_amdgcn_mfma_f32_16x16x32_bf16(ap[tm], bv[tn],
                                                                 oacc[tm][tn], 0, 0, 0);
    }
  }

  // reduce l over the 16-lane r15 group, fold sink, normalize, store bf16
#pragma unroll
  for (int i = 0; i < 8; ++i) {
    float v = lf[i];
    v += __shfl_xor(v, 1, 64);
    v += __shfl_xor(v, 2, 64);
    v += __shfl_xor(v, 4, 64);
    v += __shfl_xor(v, 8, 64);
    lf[i] = v;
  }
  const int h = kv * 4 + m;
  const float snk = __expf(sinks[h]);
#pragma unroll
  for (int tm = 0; tm < 2; ++tm)
#pragma unroll
    for (int v = 0; v < 4; ++v) {
      const float inv = 1.f / (lf[tm * 4 + v] + snk);
      const int t = t0 + tm * 16 + quad * 4 + v;
      short* op = attn_out + (size_t)(b * T_ + t) * DM + h * 64;
#pragma unroll
      for (int tn = 0; tn < 4; ++tn)
        op[tn * 16 + r15] = f2bf(oacc[tm][tn][v] * inv);
    }
}

extern "C" void kernel_launch(void* const* d_in, const int* in_sizes, int n_in,
                              void* d_out, int out_size, void* d_ws, size_t ws_size,
                              hipStream_t stream) {
  const float* x      = (const float*)d_in[0];   // fp32 (B,T,DM)
  const float* qkv_w  = (const float*)d_in[1];   // fp32 (3072,2048)
  const float* qkv_b  = (const float*)d_in[2];   // fp32 (3072,)
  const float* out_w  = (const float*)d_in[3];   // fp32 (2048,2048)
  const float* out_b  = (const float*)d_in[4];   // fp32 (2048,)
  const float* sinks  = (const float*)d_in[5];   // fp32 (32,)

  // ws layout (67.1 MB):
  //   [0, 25165824)            qkvb bf16 (4096 x 3072; v section unused)
  //   [25165824, 29360128)     vT bf16 [b][kv][64][1024]
  //   [29360128, 46137344)     x bf16, later aliased as attn bf16 out
  //   [46137344, 58720256)     qkv_w bf16
  //   [58720256, 67108864)     out_w bf16
  char* ws = (char*)d_ws;
  short* qkvb = (short*)ws;
  short* vT   = (short*)(ws + 25165824);
  short* xb   = (short*)(ws + 29360128);
  short* wqb  = (short*)(ws + 46137344);
  short* wob  = (short*)(ws + 58720256);
  short* attn = xb;                            // aliased: xb dead after gemm_qkv
  float* out  = (float*)d_out;

  cvt_kernel<<<14336, 256, 0, stream>>>(x, qkv_w, xb, wqb);
  gemm_qkv<<<dim3(QKVD / 128, 4096 / 128), 256, 0, stream>>>(xb, wqb, qkv_b, qkvb, vT);
  attn_kernel<<<dim3(T_ / 32, 8, B_ + 1), 256, 0, stream>>>(qkvb, vT, sinks, attn,
                                                            out_w, wob);
  gemm_out<<<dim3(DM / 128, 4096 / 128), 256, 0, stream>>>(attn, wob, out_b, out);
}

// Round 9
// 255.615 us; speedup vs baseline: 1.0190x; 1.0176x over previous
//
#include <hip/hip_runtime.h>
#include <hip/hip_bf16.h>

#define B_   4
#define T_   1024
#define DM   2048
#define QKVD 3072   // 64*(32+16)

typedef __attribute__((ext_vector_type(8))) short bf16x8;
typedef __attribute__((ext_vector_type(4))) short short4v;
typedef __attribute__((ext_vector_type(4))) float f32x4;

__device__ __forceinline__ void load_lds16(const void* g, void* l) {
  __builtin_amdgcn_global_load_lds((const __attribute__((address_space(1))) void*)g,
                                   (__attribute__((address_space(3))) void*)l, 16, 0, 0);
}

__device__ __forceinline__ short f2bf(float f) {
  __hip_bfloat16 h = __float2bfloat16(f);
  return *reinterpret_cast<short*>(&h);
}

// fp32 -> bf16 convert for x (8.4M) and qkv_w (6.3M). out_w conversion lives
// in the attn launch (z==4 stripe), overlapped with attention.
__global__ __launch_bounds__(256) void cvt_kernel(const float* __restrict__ x,
                                                  const float* __restrict__ w1,
                                                  short* __restrict__ xo,
                                                  short* __restrict__ w1o) {
  unsigned c = blockIdx.x * 256u + threadIdx.x;  // 0 .. 3670015
  const float* src;
  short* dst;
  if (c < 2097152u) {                 // x
    src = x; dst = xo;
  } else {                            // qkv_w
    c -= 2097152u; src = w1; dst = w1o;
  }
  const float4 v = ((const float4*)src)[c];
  short4v o;
  o.x = f2bf(v.x); o.y = f2bf(v.y); o.z = f2bf(v.z); o.w = f2bf(v.w);
  ((short4v*)dst)[c] = o;
}

// Shared GEMM K-loop: FROZEN at the round-0/round-6 structure (best measured
// total). 128x128 tile, BK=32, 4 waves (2Mx2N), 16 KB LDS single-buffer
// (3 blocks/CU), 2-bit XOR chunk swizzle (0 conflicts measured), 16x16x32
// MFMA, 2 barriers per K-step.
// Negative results (do NOT re-attempt without new evidence):
//  - 8-phase 256^2 template x2 (r1/r2): grid imbalance + depth-1 pipeline; no gain.
//  - 2-phase explicit dbuf (r3): runtime LDS indexing VALU blowup, regressed.
//  - triple-buffer + counted vmcnt (r5): occupancy loss 3->2 blocks/CU, -27%.
//  - 32x32x16 MFMA (r7/r8): -17% MFMA pipe but a swizzle-invariant 6.29M
//    bank-conflict-cycle tax from the split-rectangle read shape; net neutral
//    at best. 16x16's per-instruction full-rectangle coverage is conflict-free.
#define GEMM_PROLOGUE_AND_KLOOP(A_, B_ptr, K_)                                     \
  __shared__ short As[128 * 32];                                                   \
  __shared__ short Bs[128 * 32];                                                   \
  const int tid  = threadIdx.x;                                                    \
  const int lane = tid & 63;                                                       \
  const int wave = tid >> 6;                                                       \
  const int wm = wave >> 1, wn = wave & 1;                                         \
  const int r15 = lane & 15, quad = lane >> 4;                                     \
  const int m0 = blockIdx.y * 128, n0 = blockIdx.x * 128;                          \
  f32x4 acc[4][4];                                                                 \
  _Pragma("unroll") for (int i = 0; i < 4; ++i)                                    \
    _Pragma("unroll") for (int j = 0; j < 4; ++j) acc[i][j] = {0.f,0.f,0.f,0.f};   \
  const int ca0 = tid, ca1 = tid + 256;                                            \
  const int sr0 = ca0 >> 2, sr1 = ca1 >> 2;                                        \
  const int sq0 = (ca0 & 3) ^ ((sr0 >> 1) & 3);                                    \
  const int sq1 = (ca1 & 3) ^ ((sr1 >> 1) & 3);                                    \
  const short* gA0 = A_ + (size_t)(m0 + sr0) * K_ + sq0 * 8;                       \
  const short* gA1 = A_ + (size_t)(m0 + sr1) * K_ + sq1 * 8;                       \
  const short* gB0 = B_ptr + (size_t)(n0 + sr0) * K_ + sq0 * 8;                    \
  const short* gB1 = B_ptr + (size_t)(n0 + sr1) * K_ + sq1 * 8;                    \
  short* lA0 = &As[ca0 * 8];                                                       \
  short* lA1 = &As[ca1 * 8];                                                       \
  short* lB0 = &Bs[ca0 * 8];                                                       \
  short* lB1 = &Bs[ca1 * 8];                                                       \
  const int sw = (r15 >> 1) & 3;                                                   \
  const int fo = (quad ^ sw) * 8;                                                  \
  for (int k0 = 0; k0 < K_; k0 += 32) {                                            \
    __syncthreads();                                                               \
    load_lds16(gA0, lA0);                                                          \
    load_lds16(gA1, lA1);                                                          \
    load_lds16(gB0, lB0);                                                          \
    load_lds16(gB1, lB1);                                                          \
    gA0 += 32; gA1 += 32; gB0 += 32; gB1 += 32;                                    \
    __syncthreads();                                                               \
    bf16x8 af[4], bfr[4];                                                          \
    _Pragma("unroll") for (int tm = 0; tm < 4; ++tm)                               \
      af[tm] = *(const bf16x8*)&As[(wm * 64 + tm * 16 + r15) * 32 + fo];           \
    _Pragma("unroll") for (int tn = 0; tn < 4; ++tn)                               \
      bfr[tn] = *(const bf16x8*)&Bs[(wn * 64 + tn * 16 + r15) * 32 + fo];          \
    _Pragma("unroll") for (int tm = 0; tm < 4; ++tm)                               \
      _Pragma("unroll") for (int tn = 0; tn < 4; ++tn)                             \
        acc[tm][tn] = __builtin_amdgcn_mfma_f32_16x16x32_bf16(af[tm], bfr[tn],     \
                                                              acc[tm][tn], 0, 0, 0);\
  }

// QKV projection with fused bias + YaRN RoPE + SM_SCALE; q/k -> bf16 qkvb,
// v -> bf16 vT[b][kv][d][t] (transposed for attention's PV B-frags).
__global__ __launch_bounds__(256) void gemm_qkv(const short* __restrict__ A,
                                                const short* __restrict__ Bw,
                                                const float* __restrict__ bias,
                                                short* __restrict__ qkvb,
                                                short* __restrict__ vT) {
  GEMM_PROLOGUE_AND_KLOOP(A, Bw, 2048)

  if (blockIdx.x < 20) {
    // q (cols<2048) or k (2048..2559): bias + rope (+0.125 scale for q)
    const float scale = (blockIdx.x < 16) ? 0.125f : 1.0f;
    float invf[2];
#pragma unroll
    for (int tnh = 0; tnh < 2; ++tnh) {
      const float fi = (float)(tnh * 16 + r15);   // i = col & 31
      const float freq = __powf(150000.f, fi * (1.f / 32.f));
      float ramp = (fi - 4.3707300f) * (1.f / 9.3052397f);
      ramp = fminf(fmaxf(ramp, 0.f), 1.f);
      invf[tnh] = ramp / (32.f * freq) + (1.f - ramp) / freq;
    }
    float bv[4];
#pragma unroll
    for (int tn = 0; tn < 4; ++tn) bv[tn] = bias[n0 + wn * 64 + tn * 16 + r15];
#pragma unroll
    for (int tm = 0; tm < 4; ++tm)
#pragma unroll
      for (int v = 0; v < 4; ++v) {
        const int row = m0 + wm * 64 + tm * 16 + quad * 4 + v;
        const float ft = (float)(row & 1023);       // per-batch position
#pragma unroll
        for (int tnh = 0; tnh < 2; ++tnh) {
          const float ph = ft * invf[tnh];
          const float c = __cosf(ph) * 1.3465736f;  // concentration = 0.1*ln(32)+1
          const float s = __sinf(ph) * 1.3465736f;
          const float x1 = acc[tm][tnh][v] + bv[tnh];
          const float x2 = acc[tm][tnh + 2][v] + bv[tnh + 2];
          short* qp = qkvb + (size_t)row * QKVD + (n0 + wn * 64 + tnh * 16 + r15);
          qp[0]  = f2bf((x1 * c - x2 * s) * scale);
          qp[32] = f2bf((x2 * c + x1 * s) * scale);
        }
      }
  } else {
    // v (cols 2560..3071): bias, write transposed vT[b][kv][d][t], short4 packs
#pragma unroll
    for (int tn = 0; tn < 4; ++tn) {
      const int col = n0 + wn * 64 + tn * 16 + r15;
      const float bvv = bias[col];
      const int d = col & 63;
      const int kvh = (col - 2560) >> 6;
#pragma unroll
      for (int tm = 0; tm < 4; ++tm) {
        const int row = m0 + wm * 64 + tm * 16 + quad * 4;
        const int bb = row >> 10, tt = row & 1023;
        short4v st;
        st.x = f2bf(acc[tm][tn][0] + bvv);
        st.y = f2bf(acc[tm][tn][1] + bvv);
        st.z = f2bf(acc[tm][tn][2] + bvv);
        st.w = f2bf(acc[tm][tn][3] + bvv);
        *(short4v*)&vT[(size_t)((bb * 8 + kvh) * 64 + d) * 1024 + tt] = st;
      }
    }
  }
}

// Output projection: C fp32 = A bf16 * B^T bf16 + bias
__global__ __launch_bounds__(256) void gemm_out(const short* __restrict__ A,
                                                const short* __restrict__ Bw,
                                                const float* __restrict__ bias,
                                                float* __restrict__ C) {
  GEMM_PROLOGUE_AND_KLOOP(A, Bw, 2048)
#pragma unroll
  for (int tn = 0; tn < 4; ++tn) {
    const int col = n0 + wn * 64 + tn * 16 + r15;
    const float bv = bias[col];
#pragma unroll
    for (int tm = 0; tm < 4; ++tm) {
      const int row = m0 + wm * 64 + tm * 16 + quad * 4;
#pragma unroll
      for (int v = 0; v < 4; ++v)
        C[(size_t)(row + v) * DM + col] = acc[tm][tn][v] + bv;
    }
  }
}

// MFMA flash-style sliding-window attention, all-bf16 inputs.
// Block = (b, kv, 32-query tile), 4 waves = 4 GQA sub-heads, 4 blocks/CU.
// K/V staged via global_load_lds (16B) into unpadded 64-stride LDS with a
// 3-bit XOR swizzle (2-way banks = free). P per-wave in LDS padded to
// stride 72 (VALU-written). Fixed m=0 softmax (exact: shift-invariant,
// scores bounded well below exp overflow). Per-fragment dead-skip
// (uniform causal/window geometry) skips QK MFMA + exp for fully-masked
// 16x16 fragments. Grid z==4 stripe (256 blocks): out_w fp32->bf16 cvt,
// overlapped with attention (no dependency; gemm_out consumes wob next).
#define LSTR 72
__global__ __launch_bounds__(256, 4) void attn_kernel(const short* __restrict__ qkvb,
                                                      const short* __restrict__ vT,
                                                      const float* __restrict__ sinks,
                                                      short* __restrict__ attn_out,
                                                      const float* __restrict__ ow,
                                                      short* __restrict__ wob) {
  const int tid = threadIdx.x;

  if (blockIdx.z == 4) {
    // out_w conversion stripe: 256 blocks x 256 threads x 16 float4 = 2048x2048
    const unsigned id = blockIdx.y * 32u + blockIdx.x;          // 0..255
    const unsigned base = id * 4096u + (unsigned)tid;           // float4 index
#pragma unroll
    for (int k = 0; k < 16; ++k) {
      const float4 v = ((const float4*)ow)[base + k * 256u];
      short4v o;
      o.x = f2bf(v.x); o.y = f2bf(v.y); o.z = f2bf(v.z); o.w = f2bf(v.w);
      ((short4v*)wob)[base + k * 256u] = o;
    }
    return;
  }

  __shared__ short Kb[64 * 64];        // [key][dim], swizzled chunks
  __shared__ short Vt[64 * 64];        // [dim][key], swizzled chunks
  __shared__ short Pl[4][32 * LSTR];   // per-wave [query][key]
  const int lane = tid & 63;
  const int m    = tid >> 6;
  const int r15  = lane & 15, quad = lane >> 4;
  const int t0 = blockIdx.x * 32;
  const int kv = blockIdx.y;
  const int b  = blockIdx.z;
  const int swf = r15 & 7;

  bf16x8 qf[2][2];
#pragma unroll
  for (int tm = 0; tm < 2; ++tm)
#pragma unroll
    for (int kc = 0; kc < 2; ++kc)
      qf[tm][kc] = *(const bf16x8*)&qkvb[(size_t)(b * T_ + t0 + tm * 16 + r15) * QKVD
                                         + kv * 256 + m * 64 + kc * 32 + quad * 8];

  f32x4 oacc[2][4];
#pragma unroll
  for (int i = 0; i < 2; ++i)
#pragma unroll
    for (int j = 0; j < 4; ++j) oacc[i][j] = {0.f, 0.f, 0.f, 0.f};
  float lf[8];
#pragma unroll
  for (int i = 0; i < 8; ++i) lf[i] = 0.f;

  const short* kbase = qkvb + (size_t)b * T_ * QKVD + 2048 + kv * 64;
  const short* vbase = vT + (size_t)((b * 8 + kv) * 64) * 1024;

  // 64-aligned key tiles covering [max(0, t0-127), t0+31]
  const int jt_lo = (t0 >= 127) ? ((t0 - 127) >> 6) : 0;
  const int jt_hi = (t0 + 31) >> 6;

  for (int jt = jt_lo; jt <= jt_hi; ++jt) {
    const int j0 = jt * 64;
    __syncthreads();  // previous tile fully consumed
#pragma unroll
    for (int i = 0; i < 2; ++i) {
      const int c = i * 256 + tid;
      const int r = c >> 3, qs = (c & 7) ^ (r & 7);
      load_lds16(kbase + (size_t)(j0 + r) * QKVD + qs * 8, &Kb[c * 8]);
      load_lds16(vbase + (size_t)r * 1024 + j0 + qs * 8, &Vt[c * 8]);
    }
    __syncthreads();  // vmcnt(0) drain -> LDS ready

    // per-fragment validity (uniform across wave)
    bool deadf[2][4];
#pragma unroll
    for (int tm = 0; tm < 2; ++tm)
#pragma unroll
      for (int tn = 0; tn < 4; ++tn) {
        const int qlo = t0 + tm * 16, klo = j0 + tn * 16;
        deadf[tm][tn] = (klo > qlo + 15) || (klo + 15 <= qlo - 128);
      }

    // S = Q K^T : C/D layout col(key)=tn*16+r15, row(query)=tm*16+quad*4+v
    f32x4 sacc[2][4];
#pragma unroll
    for (int i = 0; i < 2; ++i)
#pragma unroll
      for (int j = 0; j < 4; ++j) sacc[i][j] = {0.f, 0.f, 0.f, 0.f};
#pragma unroll
    for (int kc = 0; kc < 2; ++kc) {
      bf16x8 bk[4];
#pragma unroll
      for (int tn = 0; tn < 4; ++tn)
        bk[tn] = *(const bf16x8*)&Kb[(tn * 16 + r15) * 64 + ((kc * 4 + quad) ^ swf) * 8];
#pragma unroll
      for (int tm = 0; tm < 2; ++tm)
#pragma unroll
        for (int tn = 0; tn < 4; ++tn)
          if (!deadf[tm][tn])
            sacc[tm][tn] = __builtin_amdgcn_mfma_f32_16x16x32_bf16(qf[tm][kc], bk[tn],
                                                                   sacc[tm][tn], 0, 0, 0);
    }

    // mask + exp + row-sum partials + P to per-wave LDS (dead frags: store 0)
    short* pl = &Pl[m][0];
#pragma unroll
    for (int tm = 0; tm < 2; ++tm)
#pragma unroll
      for (int v = 0; v < 4; ++v) {
        const int ql = tm * 16 + quad * 4 + v;
        const int t = t0 + ql;
        float lsum = 0.f;
#pragma unroll
        for (int tn = 0; tn < 4; ++tn) {
          if (deadf[tm][tn]) {
            pl[ql * LSTR + tn * 16 + r15] = 0;
          } else {
            const int j = j0 + tn * 16 + r15;
            const bool valid = (unsigned)(t - j) <= 127u;
            const float e = valid ? __expf(sacc[tm][tn][v]) : 0.f;
            lsum += e;
            pl[ql * LSTR + tn * 16 + r15] = f2bf(e);
          }
        }
        lf[tm * 4 + v] += lsum;
      }

    // O += P V (A from Pl, B from Vt; same-wave RAW via lgkmcnt)
#pragma unroll
    for (int kc = 0; kc < 2; ++kc) {
      bf16x8 ap[2], bv[4];
#pragma unroll
      for (int tm = 0; tm < 2; ++tm)
        ap[tm] = *(const bf16x8*)&pl[(tm * 16 + r15) * LSTR + kc * 32 + quad * 8];
#pragma unroll
      for (int tn = 0; tn < 4; ++tn)
        bv[tn] = *(const bf16x8*)&Vt[(tn * 16 + r15) * 64 + ((kc * 4 + quad) ^ swf) * 8];
#pragma unroll
      for (int tm = 0; tm < 2; ++tm)
#pragma unroll
        for (int tn = 0; tn < 4; ++tn)
          oacc[tm][tn] = __builtin_amdgcn_mfma_f32_16x16x32_bf16(ap[tm], bv[tn],
                                                                 oacc[tm][tn], 0, 0, 0);
    }
  }

  // reduce l over the 16-lane r15 group, fold sink, normalize, store bf16
#pragma unroll
  for (int i = 0; i < 8; ++i) {
    float v = lf[i];
    v += __shfl_xor(v, 1, 64);
    v += __shfl_xor(v, 2, 64);
    v += __shfl_xor(v, 4, 64);
    v += __shfl_xor(v, 8, 64);
    lf[i] = v;
  }
  const int h = kv * 4 + m;
  const float snk = __expf(sinks[h]);
#pragma unroll
  for (int tm = 0; tm < 2; ++tm)
#pragma unroll
    for (int v = 0; v < 4; ++v) {
      const float inv = 1.f / (lf[tm * 4 + v] + snk);
      const int t = t0 + tm * 16 + quad * 4 + v;
      short* op = attn_out + (size_t)(b * T_ + t) * DM + h * 64;
#pragma unroll
      for (int tn = 0; tn < 4; ++tn)
        op[tn * 16 + r15] = f2bf(oacc[tm][tn][v] * inv);
    }
}

extern "C" void kernel_launch(void* const* d_in, const int* in_sizes, int n_in,
                              void* d_out, int out_size, void* d_ws, size_t ws_size,
                              hipStream_t stream) {
  const float* x      = (const float*)d_in[0];   // fp32 (B,T,DM)
  const float* qkv_w  = (const float*)d_in[1];   // fp32 (3072,2048)
  const float* qkv_b  = (const float*)d_in[2];   // fp32 (3072,)
  const float* out_w  = (const float*)d_in[3];   // fp32 (2048,2048)
  const float* out_b  = (const float*)d_in[4];   // fp32 (2048,)
  const float* sinks  = (const float*)d_in[5];   // fp32 (32,)

  // ws layout (67.1 MB):
  //   [0, 25165824)            qkvb bf16 (4096 x 3072; v section unused)
  //   [25165824, 29360128)     vT bf16 [b][kv][64][1024]
  //   [29360128, 46137344)     x bf16, later aliased as attn bf16 out
  //   [46137344, 58720256)     qkv_w bf16
  //   [58720256, 67108864)     out_w bf16
  char* ws = (char*)d_ws;
  short* qkvb = (short*)ws;
  short* vT   = (short*)(ws + 25165824);
  short* xb   = (short*)(ws + 29360128);
  short* wqb  = (short*)(ws + 46137344);
  short* wob  = (short*)(ws + 58720256);
  short* attn = xb;                            // aliased: xb dead after gemm_qkv
  float* out  = (float*)d_out;

  cvt_kernel<<<14336, 256, 0, stream>>>(x, qkv_w, xb, wqb);
  gemm_qkv<<<dim3(QKVD / 128, 4096 / 128), 256, 0, stream>>>(xb, wqb, qkv_b, qkvb, vT);
  attn_kernel<<<dim3(T_ / 32, 8, B_ + 1), 256, 0, stream>>>(qkvb, vT, sinks, attn,
                                                            out_w, wob);
  gemm_out<<<dim3(DM / 128, 4096 / 128), 256, 0, stream>>>(attn, wob, out_b, out);
}